// Round 3
// baseline (138.163 us; speedup 1.0000x reference)
//
#include <hip/hip_runtime.h>

#define HW 256
#define CH 64
#define NPIX (4 * HW * HW)          // 262144 pixels
#define WS_BYTES ((size_t)NPIX * 24) // 12 u16 per pixel (9 used, 3 pad)

typedef float f4 __attribute__((ext_vector_type(4)));

// ===================== Kernel A: address precompute =====================
// One thread per (pixel, tap). Computes the deformed nearest-floor sample
// coordinate (reference semantics) and stores (y0<<8)|x0 as u16.
__global__ __launch_bounds__(256, 8) void DeformA_kernel(
    const float* __restrict__ gt,     // [256,256]
    const float* __restrict__ off,    // [4,256,256,18]
    unsigned short* __restrict__ ws)  // [NPIX][12]
{
    const unsigned g = blockIdx.x * 256u + threadIdx.x;   // < NPIX*9
    const unsigned p = g / 9u;                             // magic-mul, no div
    const int tap = (int)(g - p * 9u);
    const int i = (int)((p >> 8) & 255u);
    const int j = (int)(p & 255u);
    const int ky = tap / 3, kx = tap - ky * 3;

    const float2 o2 = *(const float2*)(off + (size_t)g * 2);

    const int iy = i + ky - 1, ix = j + kx - 1;
    const bool interior = (iy >= 0) & (iy < HW) & (ix >= 0) & (ix < HW);
    const int yi = interior ? iy : 0;
    const int xi = interior ? ix : 0;
    const float p_mask = (yi >= 1 && xi >= 1) ? gt[(yi - 1) * HW + (xi - 1)] : 0.f;

    const float yf = (float)yi, xf = (float)xi;
    const float yof = fminf(fmaxf(floorf(yf + o2.x), 0.f), 257.f);
    const float xof = fminf(fmaxf(floorf(xf + o2.y), 0.f), 257.f);
    const int yo = (int)yof, xo = (int)xof;
    const float p_mask_off = (yo >= 1 && yo <= HW && xo >= 1 && xo <= HW)
                             ? gt[(yo - 1) * HW + (xo - 1)] : 0.f;
    const float diff = (p_mask != p_mask_off) ? 1.f : 0.f;
    const float y = fminf(fmaxf(yf + o2.x * diff, 0.f), 255.f);
    const float x = fminf(fmaxf(xf + o2.y * diff, 0.f), 255.f);
    const int y0 = (int)y, x0 = (int)x;   // both in [0,255]; valid iff >=1

    ws[p * 12u + (unsigned)tap] = (unsigned short)((y0 << 8) | x0);
}

// ===================== Kernel B: gather + FMA =====================
// 256 threads = 4 waves, 4 px/wave, 16 lanes/px (lane%16 = channel quad).
// Round-2 lesson: the allocator chunks the gather batch at any launch
// bound (VGPR_Count stayed 32). Force it: 9 asm global_load_dwordx4 with
// distinct "=&v" outputs + ONE explicit s_waitcnt vmcnt(0). The waitcnt
// pass cannot see asm loads, so the drain is emitted manually;
// sched_barrier(0) after it blocks register-only consumer hoisting
// (guide rule #18).
#define G4(n) f4 v##n; { const float* ap = inb + eo[n] + co;            \
    asm volatile("global_load_dwordx4 %0, %1, off"                       \
                 : "=&v"(v##n) : "v"(ap)); }

#define ACC(n) { const float4 w = wq[(n) * 16 + t];                      \
    const float d = v##n.x * w.x + v##n.y * w.y                          \
                  + v##n.z * w.z + v##n.w * w.w;                         \
    acc += ((m >> (n)) & 1) ? d : 0.f; }

__global__ __launch_bounds__(256, 6) void DeformB_kernel(
    const float* __restrict__ inp,    // [4,256,256,64]
    const unsigned short* __restrict__ ws,
    const float* __restrict__ ker,    // [9][64]
    const float* __restrict__ bias,   // [1]
    float* __restrict__ out)          // [4,256,256]
{
    __shared__ float wlds[576];       // 9 taps x 64 ch
    const int tid = threadIdx.x;
    if (tid < 144) ((float4*)wlds)[tid] = ((const float4*)ker)[tid];
    const float4* wq = (const float4*)wlds;

    const int lane = tid & 63;
    const int wave = tid >> 6;
    const int t = lane & 15;

    // XCD swizzle: contiguous 2048-block chunk per XCD (16384 blocks)
    const int bid = blockIdx.x;
    const int vb = (bid & 7) * 2048 + (bid >> 3);
    const int p = vb * 16 + wave * 4 + (lane >> 4);

    const int bb = __builtin_amdgcn_readfirstlane(p >> 16);
    const float* inb = inp + (size_t)bb * (HW * HW * CH);

    // ---- encoded coords: 3 loads, same address across 16-lane group ----
    const uint2* e = (const uint2*)(ws + (size_t)p * 12u);
    const uint2 eA = e[0];                         // taps 0..3
    const uint2 eB = e[1];                         // taps 4..7
    const unsigned eC = *(const unsigned*)(e + 2); // tap 8 (+pad)

    unsigned enc[9];
    enc[0] = eA.x & 0xffffu; enc[1] = eA.x >> 16;
    enc[2] = eA.y & 0xffffu; enc[3] = eA.y >> 16;
    enc[4] = eB.x & 0xffffu; enc[5] = eB.x >> 16;
    enc[6] = eB.y & 0xffffu; enc[7] = eB.y >> 16;
    enc[8] = eC & 0xffffu;

    int m = 0;
    int eo[9];
    #pragma unroll
    for (int k = 0; k < 9; ++k) {
        const int yy = (int)(enc[k] >> 8);
        const int xx = (int)(enc[k] & 255u);
        const bool valid = (yy >= 1) & (xx >= 1);
        m |= (int)valid << k;
        eo[k] = valid ? ((yy - 1) * HW + (xx - 1)) * CH : 0;
    }

    // ---- all 9 gathers forced into one batch (36 data VGPRs live) ----
    const int co = t * 4;
    G4(0) G4(1) G4(2) G4(3) G4(4) G4(5) G4(6) G4(7) G4(8)

    asm volatile("s_waitcnt vmcnt(0)" ::: "memory");
    __builtin_amdgcn_sched_barrier(0);

    __syncthreads();                  // weights staged

    float acc = 0.f;
    ACC(0) ACC(1) ACC(2) ACC(3) ACC(4) ACC(5) ACC(6) ACC(7) ACC(8)

    acc += __shfl_xor(acc, 8);
    acc += __shfl_xor(acc, 4);
    acc += __shfl_xor(acc, 2);
    acc += __shfl_xor(acc, 1);
    if (t == 0) out[p] = acc + bias[0];
}

// ===================== Fallback (round-0 verified kernel) =====================
__global__ __launch_bounds__(256, 6) void DeformFallback_kernel(
    const float* __restrict__ inp, const float* __restrict__ gt,
    const float* __restrict__ off, const float* __restrict__ ker,
    const float* __restrict__ bias, float* __restrict__ out)
{
    __shared__ float wlds[576];
    const int tid = threadIdx.x;
    if (tid < 144) ((float4*)wlds)[tid] = ((const float4*)ker)[tid];

    const int lane = tid & 63;
    const int wave = tid >> 6;
    const int q16  = lane & 48;
    const int t    = lane & 15;

    const int bid = blockIdx.x;
    const int vb  = (bid & 7) * 2048 + (bid >> 3);

    const int p = vb * 16 + wave * 4 + (q16 >> 4);
    const int b = p >> 16;
    const int i = (p >> 8) & 255;
    const int j = p & 255;
    const float* inb = inp + (long)b * (HW * HW * CH);

    int pack = 0;
    if (t < 9) {
        const int tap = t;
        const int ky = tap / 3, kx = tap - ky * 3;
        int iy = i + ky - 1, ix = j + kx - 1;
        bool interior = (iy >= 0) & (iy < HW) & (ix >= 0) & (ix < HW);
        int yi = interior ? iy : 0;
        int xi = interior ? ix : 0;
        float p_mask = (yi >= 1 && xi >= 1) ? gt[(yi - 1) * HW + (xi - 1)] : 0.f;
        float2 o2 = *(const float2*)(off + (long)p * 18 + 2 * tap);
        float yf = (float)yi, xf = (float)xi;
        float yof = fminf(fmaxf(floorf(yf + o2.x), 0.f), 257.f);
        float xof = fminf(fmaxf(floorf(xf + o2.y), 0.f), 257.f);
        int yo = (int)yof, xo = (int)xof;
        float p_mask_off = (yo >= 1 && yo <= HW && xo >= 1 && xo <= HW)
                           ? gt[(yo - 1) * HW + (xo - 1)] : 0.f;
        float diff = (p_mask != p_mask_off) ? 1.f : 0.f;
        float y = fminf(fmaxf(yf + o2.x * diff, 0.f), 255.f);
        float x = fminf(fmaxf(xf + o2.y * diff, 0.f), 255.f);
        int y0 = (int)y;
        int x0 = (int)x;
        bool valid = (y0 >= 1) & (x0 >= 1);
        int eoff = ((y0 - 1) * HW + (x0 - 1)) * CH;
        pack = valid ? eoff : -1;
    }

    int pk[9];
    #pragma unroll
    for (int k = 0; k < 9; ++k) pk[k] = __shfl(pack, q16 + k);

    float4 v[9];
    #pragma unroll
    for (int k = 0; k < 9; ++k) {
        int eo2 = pk[k] >= 0 ? pk[k] : 0;
        v[k] = *(const float4*)(inb + eo2 + t * 4);
    }

    __syncthreads();

    float acc = 0.f;
    #pragma unroll
    for (int k = 0; k < 9; ++k) {
        float s = pk[k] >= 0 ? 1.f : 0.f;
        float4 w = ((const float4*)wlds)[k * 16 + t];
        float d = v[k].x * w.x + v[k].y * w.y + v[k].z * w.z + v[k].w * w.w;
        acc = fmaf(s, d, acc);
    }

    acc += __shfl_xor(acc, 8);
    acc += __shfl_xor(acc, 4);
    acc += __shfl_xor(acc, 2);
    acc += __shfl_xor(acc, 1);
    if (t == 0) out[p] = acc + bias[0];
}

extern "C" void kernel_launch(void* const* d_in, const int* in_sizes, int n_in,
                              void* d_out, int out_size, void* d_ws, size_t ws_size,
                              hipStream_t stream) {
    const float* inp  = (const float*)d_in[0];
    const float* gt   = (const float*)d_in[1];
    const float* off  = (const float*)d_in[2];
    const float* ker  = (const float*)d_in[3];
    const float* bias = (const float*)d_in[4];
    float* out = (float*)d_out;

    if (d_ws != nullptr && ws_size >= WS_BYTES) {
        DeformA_kernel<<<9216, 256, 0, stream>>>(gt, off, (unsigned short*)d_ws);
        DeformB_kernel<<<16384, 256, 0, stream>>>(
            inp, (const unsigned short*)d_ws, ker, bias, out);
    } else {
        DeformFallback_kernel<<<16384, 256, 0, stream>>>(inp, gt, off, ker, bias, out);
    }
}

// Round 4
// 135.306 us; speedup vs baseline: 1.0211x; 1.0211x over previous
//
#include <hip/hip_runtime.h>

#define HW 256
#define CH 64
#define NPIX (4 * HW * HW)            // 262144 pixels
#define DM_BYTES ((size_t)NPIX * 48)  // 12 floats per pixel (9 used, 3 pad)

// ===================== Kernel D: per-position tap dot-products =====================
// dm[p][k] = sum_c inp[p][c] * ker[k][c]  (9-channel pointwise conv).
// 256 thr = 4 waves; 16 lanes per pixel (t = lane&15 = channel quad),
// 2 pixels per 16-lane group (shares the 9 LDS weight reads), 32 px/block.
// Reads are fully coalesced; this kernel is pure streaming + VALU.
__global__ __launch_bounds__(256, 8) void DeformD_kernel(
    const float* __restrict__ inp,    // [NPIX][64]
    const float* __restrict__ ker,    // [9][64]
    float* __restrict__ dm)           // [NPIX][12]
{
    __shared__ float wlds[576];       // 9 taps x 64 ch
    const int tid = threadIdx.x;
    if (tid < 144) ((float4*)wlds)[tid] = ((const float4*)ker)[tid];
    const float4* wq = (const float4*)wlds;

    const int lane = tid & 63;
    const int wave = tid >> 6;
    const int t = lane & 15;
    const int g = lane >> 4;

    const int p0 = blockIdx.x * 32 + (wave * 4 + g) * 2;   // pixels p0, p0+1

    const float4 v0 = *(const float4*)(inp + (size_t)p0 * 64 + t * 4);
    const float4 v1 = *(const float4*)(inp + (size_t)(p0 + 1) * 64 + t * 4);

    __syncthreads();                  // weights staged

    float da[9], db[9];
    #pragma unroll
    for (int k = 0; k < 9; ++k) {
        const float4 w = wq[k * 16 + t];
        da[k] = v0.x * w.x + v0.y * w.y + v0.z * w.z + v0.w * w.w;
        db[k] = v1.x * w.x + v1.y * w.y + v1.z * w.z + v1.w * w.w;
    }
    // 16-lane tree reduce per tap (xor masks stay inside the 16-group)
    #pragma unroll
    for (int k = 0; k < 9; ++k) {
        da[k] += __shfl_xor(da[k], 8);
        da[k] += __shfl_xor(da[k], 4);
        da[k] += __shfl_xor(da[k], 2);
        da[k] += __shfl_xor(da[k], 1);
        db[k] += __shfl_xor(db[k], 8);
        db[k] += __shfl_xor(db[k], 4);
        db[k] += __shfl_xor(db[k], 2);
        db[k] += __shfl_xor(db[k], 1);
    }
    // lane t stores tap t (static select chain, no runtime indexing)
    float sa = da[8], sb = db[8];
    #pragma unroll
    for (int k = 7; k >= 0; --k) {
        sa = (t == k) ? da[k] : sa;
        sb = (t == k) ? db[k] : sb;
    }
    if (t < 9) {
        dm[(size_t)p0 * 12 + t] = sa;
        dm[(size_t)(p0 + 1) * 12 + t] = sb;
    }
}

// ===================== Kernel C: deformable gather of dot-products =====================
// One thread per output pixel. Recomputes the (verified) address math for
// all 9 taps, gathers ONE float per tap from dm (4B instead of 256B),
// sums, stores. All 9 tap chains are independent — compiler interleaves.
__global__ __launch_bounds__(256, 4) void DeformC_kernel(
    const float* __restrict__ gt,     // [256,256]
    const float* __restrict__ off,    // [4,256,256,18]
    const float* __restrict__ dm,     // [NPIX][12]
    const float* __restrict__ bias,   // [1]
    float* __restrict__ out)          // [4,256,256]
{
    const int tid = threadIdx.x;
    const int bid = blockIdx.x;
    // XCD swizzle: contiguous 128-block chunk per XCD (1024 blocks)
    const int vb = (bid & 7) * 128 + (bid >> 3);
    const int p = vb * 256 + tid;
    const int b = p >> 16;
    const int i = (p >> 8) & 255;
    const int j = p & 255;

    // all 9 offset pairs up front (contiguous 72B per thread, batched)
    const float* offp = off + (size_t)p * 18;
    float2 o[9];
    #pragma unroll
    for (int tap = 0; tap < 9; ++tap)
        o[tap] = *(const float2*)(offp + 2 * tap);

    const float* dmb = dm + (size_t)(b << 16) * 12;

    float sum = 0.f;
    #pragma unroll
    for (int tap = 0; tap < 9; ++tap) {
        const int ky = tap / 3, kx = tap - ky * 3;
        const int iy = i + ky - 1, ix = j + kx - 1;
        const bool interior = (iy >= 0) & (iy < HW) & (ix >= 0) & (ix < HW);
        const int yi = interior ? iy : 0;
        const int xi = interior ? ix : 0;
        const float p_mask = (yi >= 1 && xi >= 1) ? gt[(yi - 1) * HW + (xi - 1)] : 0.f;

        const float yf = (float)yi, xf = (float)xi;
        const float yof = fminf(fmaxf(floorf(yf + o[tap].x), 0.f), 257.f);
        const float xof = fminf(fmaxf(floorf(xf + o[tap].y), 0.f), 257.f);
        const int yo = (int)yof, xo = (int)xof;
        const float p_mask_off = (yo >= 1 && yo <= HW && xo >= 1 && xo <= HW)
                                 ? gt[(yo - 1) * HW + (xo - 1)] : 0.f;
        const float diff = (p_mask != p_mask_off) ? 1.f : 0.f;
        const float y = fminf(fmaxf(yf + o[tap].x * diff, 0.f), 255.f);
        const float x = fminf(fmaxf(xf + o[tap].y * diff, 0.f), 255.f);
        const int y0 = (int)y, x0 = (int)x;
        const bool valid = (y0 >= 1) & (x0 >= 1);
        const int idx = valid ? ((y0 - 1) * HW + (x0 - 1)) : 0;
        const float dval = dmb[(size_t)idx * 12 + tap];
        sum += valid ? dval : 0.f;
    }
    out[p] = sum + bias[0];
}

// ===================== Fallback (round-0 verified kernel) =====================
__global__ __launch_bounds__(256, 6) void DeformFallback_kernel(
    const float* __restrict__ inp, const float* __restrict__ gt,
    const float* __restrict__ off, const float* __restrict__ ker,
    const float* __restrict__ bias, float* __restrict__ out)
{
    __shared__ float wlds[576];
    const int tid = threadIdx.x;
    if (tid < 144) ((float4*)wlds)[tid] = ((const float4*)ker)[tid];

    const int lane = tid & 63;
    const int wave = tid >> 6;
    const int q16  = lane & 48;
    const int t    = lane & 15;

    const int bid = blockIdx.x;
    const int vb  = (bid & 7) * 2048 + (bid >> 3);

    const int p = vb * 16 + wave * 4 + (q16 >> 4);
    const int b = p >> 16;
    const int i = (p >> 8) & 255;
    const int j = p & 255;
    const float* inb = inp + (long)b * (HW * HW * CH);

    int pack = 0;
    if (t < 9) {
        const int tap = t;
        const int ky = tap / 3, kx = tap - ky * 3;
        int iy = i + ky - 1, ix = j + kx - 1;
        bool interior = (iy >= 0) & (iy < HW) & (ix >= 0) & (ix < HW);
        int yi = interior ? iy : 0;
        int xi = interior ? ix : 0;
        float p_mask = (yi >= 1 && xi >= 1) ? gt[(yi - 1) * HW + (xi - 1)] : 0.f;
        float2 o2 = *(const float2*)(off + (long)p * 18 + 2 * tap);
        float yf = (float)yi, xf = (float)xi;
        float yof = fminf(fmaxf(floorf(yf + o2.x), 0.f), 257.f);
        float xof = fminf(fmaxf(floorf(xf + o2.y), 0.f), 257.f);
        int yo = (int)yof, xo = (int)xof;
        float p_mask_off = (yo >= 1 && yo <= HW && xo >= 1 && xo <= HW)
                           ? gt[(yo - 1) * HW + (xo - 1)] : 0.f;
        float diff = (p_mask != p_mask_off) ? 1.f : 0.f;
        float y = fminf(fmaxf(yf + o2.x * diff, 0.f), 255.f);
        float x = fminf(fmaxf(xf + o2.y * diff, 0.f), 255.f);
        int y0 = (int)y;
        int x0 = (int)x;
        bool valid = (y0 >= 1) & (x0 >= 1);
        int eoff = ((y0 - 1) * HW + (x0 - 1)) * CH;
        pack = valid ? eoff : -1;
    }

    int pk[9];
    #pragma unroll
    for (int k = 0; k < 9; ++k) pk[k] = __shfl(pack, q16 + k);

    float4 v[9];
    #pragma unroll
    for (int k = 0; k < 9; ++k) {
        int eo2 = pk[k] >= 0 ? pk[k] : 0;
        v[k] = *(const float4*)(inb + eo2 + t * 4);
    }

    __syncthreads();

    float acc = 0.f;
    #pragma unroll
    for (int k = 0; k < 9; ++k) {
        float s = pk[k] >= 0 ? 1.f : 0.f;
        float4 w = ((const float4*)wlds)[k * 16 + t];
        float d = v[k].x * w.x + v[k].y * w.y + v[k].z * w.z + v[k].w * w.w;
        acc = fmaf(s, d, acc);
    }

    acc += __shfl_xor(acc, 8);
    acc += __shfl_xor(acc, 4);
    acc += __shfl_xor(acc, 2);
    acc += __shfl_xor(acc, 1);
    if (t == 0) out[p] = acc + bias[0];
}

extern "C" void kernel_launch(void* const* d_in, const int* in_sizes, int n_in,
                              void* d_out, int out_size, void* d_ws, size_t ws_size,
                              hipStream_t stream) {
    const float* inp  = (const float*)d_in[0];
    const float* gt   = (const float*)d_in[1];
    const float* off  = (const float*)d_in[2];
    const float* ker  = (const float*)d_in[3];
    const float* bias = (const float*)d_in[4];
    float* out = (float*)d_out;

    if (d_ws != nullptr && ws_size >= DM_BYTES) {
        // D: 262144 px / 32 per block = 8192 blocks
        DeformD_kernel<<<8192, 256, 0, stream>>>(inp, ker, (float*)d_ws);
        // C: 262144 px / 256 per block = 1024 blocks
        DeformC_kernel<<<1024, 256, 0, stream>>>(gt, off, (const float*)d_ws, bias, out);
    } else {
        DeformFallback_kernel<<<16384, 256, 0, stream>>>(inp, gt, off, ker, bias, out);
    }
}